// Round 5
// baseline (386.431 us; speedup 1.0000x reference)
//
#include <hip/hip_runtime.h>

// Problem constants (match reference).
#define BB 4
#define CC 64
#define HH 512
#define WW 512
#define PP 409600

#define TILE 256   // x-cells per workgroup in phase 2
#define NT   512   // threads per block in phase 2
#define SMS  257   // LDS row stride (floats) for [c][x]; odd -> gather writes
                   // land 2-way-conflicted (free), reads 4-way (1.58x)

// Native Clang vector types (HIP_vector_type rejected by nontemporal builtins).
typedef float vfloat4 __attribute__((ext_vector_type(4)));
typedef int   vint4   __attribute__((ext_vector_type(4)));

// Phase 1: last-write-wins winner selection. Highest pillar index wins,
// matching sequential-assignment semantics.
__global__ void pillar_winner_kernel(const vint4* __restrict__ coords,
                                     int* __restrict__ winner) {
    int p = blockIdx.x * blockDim.x + threadIdx.x;
    if (p >= PP) return;
    vint4 c = coords[p];                // [b, z, y, x]
    int b = c.x, y = c.z, x = c.w;
    if ((unsigned)y < (unsigned)HH && (unsigned)x < (unsigned)WW &&
        (unsigned)b < (unsigned)BB) {
        int flat = (b * HH + y) * WW + x;
        atomicMax(&winner[flat], p);
    }
}

// Phase 2 (LDS-staged): one 512-thread block per 256 consecutive x-cells of
// one (b, y) row. Gather winner feature rows with 16 CONTIGUOUS lanes per row
// (256 B per row fully consumed by one instruction), transpose via LDS,
// write 1 KiB contiguous per channel-plane segment (vs 512 B before) for
// better HBM write locality. LDS 66 KiB -> 2 blocks/CU = 16 waves/CU.
__launch_bounds__(NT, 4)
__global__ void canvas_write_kernel(const float* __restrict__ feat,
                                    const int* __restrict__ winner,
                                    float* __restrict__ out) {
    __shared__ float smem[CC * SMS];   // [c][x], padded stride
    __shared__ int   swin[TILE];

    int blk  = blockIdx.x;                 // over B*H*(W/TILE) = 4096
    int tx   = blk & (WW / TILE - 1);      // 0..1
    int rest = blk >> 1;
    int y    = rest & (HH - 1);            // 0..511
    int b    = rest >> 9;                  // 0..3

    int tid = threadIdx.x;
    int cellbase = (b * HH + y) * WW + tx * TILE;

    // Stage 256 winner ids: 64 lanes x int4.
    if (tid < TILE / 4)
        ((vint4*)swin)[tid] = *((const vint4*)(winner + cellbase) + tid);
    __syncthreads();

    const vfloat4* fq  = (const vfloat4*)feat;  // rows: CC/4 float4 each
    const vfloat4 zero = (vfloat4)(0.f);

    // Gather: 256 rows x 16 float4 = 4096 loads; 8 per thread.
    // Lanes 0-15 read row r's float4 0..15 (256 B contiguous), etc.
    // LDS write bank = (4k + j + r) mod 32 -> 32 banks x2 = 2-way (free).
#pragma unroll
    for (int i = 0; i < 8; ++i) {
        int flat = i * NT + tid;
        int r = flat >> 4;                 // cell within tile (0..255)
        int k = flat & 15;                 // float4 component (0..15)
        int w = swin[r];
        vfloat4 v = (w >= 0) ? fq[w * (CC / 4) + k] : zero;
        int c0 = 4 * k;
        smem[(c0 + 0) * SMS + r] = v.x;
        smem[(c0 + 1) * SMS + r] = v.y;
        smem[(c0 + 2) * SMS + r] = v.z;
        smem[(c0 + 3) * SMS + r] = v.w;
    }
    __syncthreads();

    // Store: 64 channels x 64 float4-groups = 4096 stores; 8 per thread.
    // Mapping keeps 2 channels per wave (half-wave each) so LDS reads stay
    // 4-way: c = i*8 + (halfwave&7); xg = (tid&31) + 32*(tid>>8).
#pragma unroll
    for (int i = 0; i < 8; ++i) {
        int h  = tid >> 5;                 // half-wave id 0..15
        int c  = i * 8 + (h & 7);          // 0..63
        int xg = (tid & 31) + 32 * (tid >> 8);  // 0..63
        vfloat4 o;
        o.x = smem[c * SMS + 4 * xg + 0];
        o.y = smem[c * SMS + 4 * xg + 1];
        o.z = smem[c * SMS + 4 * xg + 2];
        o.w = smem[c * SMS + 4 * xg + 3];
        int addr = ((b * CC + c) * HH + y) * WW + tx * TILE + 4 * xg;
        *(vfloat4*)(out + addr) = o;
    }
}

extern "C" void kernel_launch(void* const* d_in, const int* in_sizes, int n_in,
                              void* d_out, int out_size, void* d_ws, size_t ws_size,
                              hipStream_t stream) {
    const float* feat   = (const float*)d_in[0];   // [P, C] fp32
    const vint4* coords = (const vint4*)d_in[1];   // [P, 4] int32
    float* out          = (float*)d_out;           // [B, C, H, W] fp32
    int* winner         = (int*)d_ws;              // [B*H*W] int32 (4 MiB)

    // winner = -1 everywhere (0xFF bytes).
    (void)hipMemsetAsync(winner, 0xFF, (size_t)BB * HH * WW * sizeof(int), stream);

    // Phase 1: winner selection.
    {
        int threads = 256;
        int blocks = (PP + threads - 1) / threads;
        pillar_winner_kernel<<<blocks, threads, 0, stream>>>(coords, winner);
    }

    // Phase 2: LDS-staged canvas write.
    {
        int blocks = BB * HH * (WW / TILE);        // 4096
        canvas_write_kernel<<<blocks, NT, 0, stream>>>(feat, winner, out);
    }
}